// Round 1
// baseline (165.530 us; speedup 1.0000x reference)
//
#include <hip/hip_runtime.h>
#include <hip/hip_bf16.h>

#define B_ 2
#define N_ 2048
#define FIN 512
#define H_ 8
#define DH 64
#define HD 512 /* H_*DH */
#define SLOPE 0.2f
#define NCHUNK 32
#define CH 64

__device__ __forceinline__ float wave_sum(float v) {
#pragma unroll
  for (int off = 32; off > 0; off >>= 1) v += __shfl_xor(v, off, 64);
  return v;
}

// K1: g = f @ W   (M=B*N=4096, K=512, N=512), fp32, 64x64 tile, 4x4 per thread
__global__ __launch_bounds__(256) void k_gemm(const float* __restrict__ A,
                                              const float* __restrict__ W,
                                              float* __restrict__ C) {
  __shared__ float As[16][64];  // K-major (transposed) for float4 reads
  __shared__ float Bs[16][64];
  const int tid = threadIdx.x;
  const int row0 = blockIdx.y * 64;
  const int col0 = blockIdx.x * 64;
  const int ar = tid >> 2;          // 0..63
  const int ac = (tid & 3) << 2;    // 0,4,8,12
  const int br = tid >> 4;          // 0..15
  const int bc = (tid & 15) << 2;   // 0..60
  const int ty4 = (tid >> 4) << 2;  // row group
  const int tx4 = (tid & 15) << 2;  // col group
  float acc[4][4] = {};
  const float* Ap = A + (row0 + ar) * FIN + ac;
  const float* Wp = W + br * HD + col0 + bc;
  for (int k0 = 0; k0 < FIN; k0 += 16) {
    const float4 av = *(const float4*)(Ap + k0);
    const float4 bv = *(const float4*)(Wp + k0 * HD);
    __syncthreads();
    As[ac + 0][ar] = av.x;
    As[ac + 1][ar] = av.y;
    As[ac + 2][ar] = av.z;
    As[ac + 3][ar] = av.w;
    *(float4*)&Bs[br][bc] = bv;
    __syncthreads();
#pragma unroll
    for (int kk = 0; kk < 16; ++kk) {
      const float4 a4 = *(const float4*)&As[kk][ty4];
      const float4 b4 = *(const float4*)&Bs[kk][tx4];
      acc[0][0] = fmaf(a4.x, b4.x, acc[0][0]);
      acc[0][1] = fmaf(a4.x, b4.y, acc[0][1]);
      acc[0][2] = fmaf(a4.x, b4.z, acc[0][2]);
      acc[0][3] = fmaf(a4.x, b4.w, acc[0][3]);
      acc[1][0] = fmaf(a4.y, b4.x, acc[1][0]);
      acc[1][1] = fmaf(a4.y, b4.y, acc[1][1]);
      acc[1][2] = fmaf(a4.y, b4.z, acc[1][2]);
      acc[1][3] = fmaf(a4.y, b4.w, acc[1][3]);
      acc[2][0] = fmaf(a4.z, b4.x, acc[2][0]);
      acc[2][1] = fmaf(a4.z, b4.y, acc[2][1]);
      acc[2][2] = fmaf(a4.z, b4.z, acc[2][2]);
      acc[2][3] = fmaf(a4.z, b4.w, acc[2][3]);
      acc[3][0] = fmaf(a4.w, b4.x, acc[3][0]);
      acc[3][1] = fmaf(a4.w, b4.y, acc[3][1]);
      acc[3][2] = fmaf(a4.w, b4.z, acc[3][2]);
      acc[3][3] = fmaf(a4.w, b4.w, acc[3][3]);
    }
  }
#pragma unroll
  for (int i2 = 0; i2 < 4; ++i2) {
    float4 o;
    o.x = acc[i2][0]; o.y = acc[i2][1]; o.z = acc[i2][2]; o.w = acc[i2][3];
    *(float4*)&C[(row0 + ty4 + i2) * HD + col0 + tx4] = o;
  }
}

// K2: sl[b,h,i] = g[b,i,h,:].a_l ; sr[b,h,j] = g[b,j,h,:].a_r  (one wave per (b,n,h))
__global__ __launch_bounds__(256) void k_scores(const float* __restrict__ g,
                                                const float* __restrict__ aw,
                                                float* __restrict__ sl,
                                                float* __restrict__ sr) {
  const int wv = blockIdx.x * 4 + (threadIdx.x >> 6);
  const int lane = threadIdx.x & 63;
  const int h = wv & 7;
  const int row = wv >> 3;  // b*N + n
  const float x = g[row * HD + h * DH + lane];
  const float s1 = wave_sum(x * aw[lane]);
  const float s2 = wave_sum(x * aw[DH + lane]);
  if (lane == 0) {
    const int b = row >> 11, n = row & (N_ - 1);
    sl[(b * H_ + h) * N_ + n] = s1;
    sr[(b * H_ + h) * N_ + n] = s2;
  }
}

// K3: bitonic sort of sr per (b,h), ascending, with original-index payload
__global__ __launch_bounds__(1024) void k_sort(const float* __restrict__ sr,
                                               float* __restrict__ sv,
                                               int* __restrict__ si) {
  __shared__ float v[2048];
  __shared__ int ix[2048];
  const int t = threadIdx.x;
  const int base = blockIdx.x * N_;
  v[t] = sr[base + t];
  v[t + 1024] = sr[base + t + 1024];
  ix[t] = t;
  ix[t + 1024] = t + 1024;
  __syncthreads();
  for (int k = 2; k <= 2048; k <<= 1) {
    for (int j = k >> 1; j > 0; j >>= 1) {
      const int i = ((t & ~(j - 1)) << 1) | (t & (j - 1));
      const int p = i | j;
      const bool up = ((i & k) == 0);
      const float a = v[i], b2 = v[p];
      if ((a > b2) == up) {
        v[i] = b2; v[p] = a;
        const int tmp = ix[i]; ix[i] = ix[p]; ix[p] = tmp;
      }
      __syncthreads();
    }
  }
  sv[base + t] = v[t];
  sv[base + t + 1024] = v[t + 1024];
  si[base + t] = ix[t];
  si[base + t + 1024] = ix[t + 1024];
}

// K4: per (b,h,chunk): w1=exp(sr-m), w2=exp(0.2(sr-m)); chunk vector sums of w*g
__global__ __launch_bounds__(64) void k_chunks(const float* __restrict__ g,
                                               const float* __restrict__ sv,
                                               const int* __restrict__ si,
                                               float* __restrict__ w1,
                                               float* __restrict__ w2,
                                               float* __restrict__ C1,
                                               float* __restrict__ C2,
                                               float* __restrict__ Zc1,
                                               float* __restrict__ Zc2) {
  const int bh = blockIdx.x >> 5;
  const int c = blockIdx.x & 31;
  const int b = bh >> 3, h = bh & 7;
  const int lane = threadIdx.x;
  const int base = bh * N_;
  const int t = c * CH + lane;
  const float m = sv[base + N_ - 1];
  const float val = sv[base + t];
  const float e1 = __expf(val - m);
  const float e2 = __expf(SLOPE * (val - m));
  w1[base + t] = e1;
  w2[base + t] = e2;
  const int jv = si[base + t];
  float acc1 = 0.f, acc2 = 0.f;
#pragma unroll 8
  for (int u = 0; u < CH; ++u) {
    const float wa = __shfl(e1, u, 64);
    const float wb = __shfl(e2, u, 64);
    const int j = __shfl(jv, u, 64);
    const float gv = g[(b * N_ + j) * HD + h * DH + lane];
    acc1 = fmaf(wa, gv, acc1);
    acc2 = fmaf(wb, gv, acc2);
  }
  C1[blockIdx.x * 64 + lane] = acc1;
  C2[blockIdx.x * 64 + lane] = acc2;
  const float z1 = wave_sum(e1);
  const float z2 = wave_sum(e2);
  if (lane == 0) { Zc1[blockIdx.x] = z1; Zc2[blockIdx.x] = z2; }
}

// K5: exclusive scan of chunk sums (33 entries incl. total), per (b,h)
__global__ __launch_bounds__(64) void k_scan(const float* __restrict__ C1,
                                             const float* __restrict__ C2,
                                             const float* __restrict__ Zc1,
                                             const float* __restrict__ Zc2,
                                             float* __restrict__ U1,
                                             float* __restrict__ U2,
                                             float* __restrict__ Zb1,
                                             float* __restrict__ Zb2) {
  const int bh = blockIdx.x;
  const int d = threadIdx.x;
  float r1 = 0.f, r2 = 0.f;
  for (int c = 0; c < NCHUNK; ++c) {
    U1[(bh * 33 + c) * 64 + d] = r1;
    U2[(bh * 33 + c) * 64 + d] = r2;
    r1 += C1[(bh * 32 + c) * 64 + d];
    r2 += C2[(bh * 32 + c) * 64 + d];
  }
  U1[(bh * 33 + 32) * 64 + d] = r1;
  U2[(bh * 33 + 32) * 64 + d] = r2;
  if (d == 0) {
    float z1 = 0.f, z2 = 0.f;
    for (int c = 0; c < NCHUNK; ++c) {
      Zb1[bh * 33 + c] = z1;
      Zb2[bh * 33 + c] = z2;
      z1 += Zc1[bh * 32 + c];
      z2 += Zc2[bh * 32 + c];
    }
    Zb1[bh * 33 + 32] = z1;
    Zb2[bh * 33 + 32] = z2;
  }
}

// K6: per row i: binary-search split p, combine chunk bases + <=63 fixup terms
__global__ __launch_bounds__(256) void k_out(const float* __restrict__ g,
                                             const float* __restrict__ sl,
                                             const float* __restrict__ sv,
                                             const int* __restrict__ si,
                                             const float* __restrict__ w1,
                                             const float* __restrict__ w2,
                                             const float* __restrict__ U1,
                                             const float* __restrict__ U2,
                                             const float* __restrict__ Zb1,
                                             const float* __restrict__ Zb2,
                                             float* __restrict__ out) {
  const int wv = blockIdx.x * 4 + (threadIdx.x >> 6);
  const int d = threadIdx.x & 63;
  const int h = wv & 7;
  const int row = wv >> 3;
  const int b = row >> 11;
  const int i = row & (N_ - 1);
  const int bh = b * H_ + h;
  const int base = bh * N_;
  const float sli = sl[base + i];
  const float m = sv[base + N_ - 1];
  const float th = -sli;
  int lo = 0, hi = N_;
  while (lo < hi) {
    const int mid = (lo + hi) >> 1;
    if (sv[base + mid] < th) lo = mid + 1; else hi = mid;
  }
  const int p = lo;                         // first idx with sr >= -sl (positive branch)
  const float slm = sli + m;
  const float M = slm >= 0.f ? slm : SLOPE * slm;  // row max of e
  const float c1 = __expf(slm - M);         // scale for positive branch (<=1)
  const float c2 = __expf(SLOPE * slm - M); // scale for negative branch (<=1)
  const int c = p >> 6;
  const int r = p & 63;
  const float tot1 = U1[(bh * 33 + 32) * 64 + d];
  const float b1 = U1[(bh * 33 + c) * 64 + d];
  const float b2 = U2[(bh * 33 + c) * 64 + d];
  const float zt1 = Zb1[bh * 33 + 32];
  const float zb1 = Zb1[bh * 33 + c];
  const float zb2 = Zb2[bh * 33 + c];
  float p1 = 0.f, p2 = 0.f, zp1 = 0.f, zp2 = 0.f;
  for (int u = 0; u < r; ++u) {
    const int q = c * CH + u;
    const float wa = w1[base + q];
    const float wb = w2[base + q];
    const int j = si[base + q];
    const float gv = g[(b * N_ + j) * HD + h * DH + d];
    p1 = fmaf(wa, gv, p1);
    p2 = fmaf(wb, gv, p2);
    zp1 += wa;
    zp2 += wb;
  }
  const float S1 = tot1 - b1 - p1;  // suffix vector sum (positive set)
  const float P2v = b2 + p2;        // prefix vector sum (negative set)
  const float Z = c1 * (zt1 - zb1 - zp1) + c2 * (zb2 + zp2);  // Z >= 1 always
  out[row * HD + h * DH + d] = (c1 * S1 + c2 * P2v) / Z;
}

extern "C" void kernel_launch(void* const* d_in, const int* in_sizes, int n_in,
                              void* d_out, int out_size, void* d_ws, size_t ws_size,
                              hipStream_t stream) {
  const float* f = (const float*)d_in[0];
  // d_in[1] = adj_mat (all ones, unused by reference math)
  const float* W = (const float*)d_in[2];
  const float* aw = (const float*)d_in[3];
  float* out = (float*)d_out;

  float* g = (float*)d_ws;                 // 2*2048*512
  float* sl = g + B_ * N_ * HD;            // 32768 each, layout [(b*H+h)*N + n]
  float* sr = sl + B_ * N_ * H_;
  float* sv = sr + B_ * N_ * H_;
  int* si = (int*)(sv + B_ * N_ * H_);
  float* w1 = (float*)(si + B_ * N_ * H_);
  float* w2 = w1 + B_ * N_ * H_;
  float* U1 = w2 + B_ * N_ * H_;           // 16*33*64 exclusive bases + total
  float* U2 = U1 + 16 * 33 * 64;
  float* Zb1 = U2 + 16 * 33 * 64;          // 16*33
  float* Zb2 = Zb1 + 16 * 33;
  float* C1 = Zb2 + 16 * 33;               // 16*32*64 chunk sums
  float* C2 = C1 + 16 * 32 * 64;
  float* Zc1 = C2 + 16 * 32 * 64;          // 16*32
  float* Zc2 = Zc1 + 16 * 32;

  hipLaunchKernelGGL(k_gemm, dim3(HD / 64, (B_ * N_) / 64), dim3(256), 0, stream, f, W, g);
  hipLaunchKernelGGL(k_scores, dim3(B_ * N_ * H_ / 4), dim3(256), 0, stream, g, aw, sl, sr);
  hipLaunchKernelGGL(k_sort, dim3(B_ * H_), dim3(1024), 0, stream, sr, sv, si);
  hipLaunchKernelGGL(k_chunks, dim3(B_ * H_ * NCHUNK), dim3(64), 0, stream, g, sv, si, w1, w2, C1, C2, Zc1, Zc2);
  hipLaunchKernelGGL(k_scan, dim3(B_ * H_), dim3(64), 0, stream, C1, C2, Zc1, Zc2, U1, U2, Zb1, Zb2);
  hipLaunchKernelGGL(k_out, dim3(B_ * N_ * H_ / 4), dim3(256), 0, stream, g, sl, sv, si, w1, w2, U1, U2, Zb1, Zb2, out);
}

// Round 2
// 93.393 us; speedup vs baseline: 1.7724x; 1.7724x over previous
//
#include <hip/hip_runtime.h>
#include <hip/hip_bf16.h>

#define B_ 2
#define N_ 2048
#define FIN 512
#define H_ 8
#define DH 64
#define HD 512 /* H_*DH */
#define SLOPE 0.2f
#define NCHUNK 32
#define CH 64

__device__ __forceinline__ float wave_sum(float v) {
#pragma unroll
  for (int off = 32; off > 0; off >>= 1) v += __shfl_xor(v, off, 64);
  return v;
}

// K1: g = f @ W   (M=B*N=4096, K=512, N=512), fp32, 64x64 tile, 4x4 per thread
__global__ __launch_bounds__(256) void k_gemm(const float* __restrict__ A,
                                              const float* __restrict__ W,
                                              float* __restrict__ C) {
  __shared__ float As[16][64];  // K-major (transposed) for float4 reads
  __shared__ float Bs[16][64];
  const int tid = threadIdx.x;
  const int row0 = blockIdx.y * 64;
  const int col0 = blockIdx.x * 64;
  const int ar = tid >> 2;          // 0..63
  const int ac = (tid & 3) << 2;    // 0,4,8,12
  const int br = tid >> 4;          // 0..15
  const int bc = (tid & 15) << 2;   // 0..60
  const int ty4 = (tid >> 4) << 2;  // row group
  const int tx4 = (tid & 15) << 2;  // col group
  float acc[4][4] = {};
  const float* Ap = A + (row0 + ar) * FIN + ac;
  const float* Wp = W + br * HD + col0 + bc;
  for (int k0 = 0; k0 < FIN; k0 += 16) {
    const float4 av = *(const float4*)(Ap + k0);
    const float4 bv = *(const float4*)(Wp + k0 * HD);
    __syncthreads();
    As[ac + 0][ar] = av.x;
    As[ac + 1][ar] = av.y;
    As[ac + 2][ar] = av.z;
    As[ac + 3][ar] = av.w;
    *(float4*)&Bs[br][bc] = bv;
    __syncthreads();
#pragma unroll
    for (int kk = 0; kk < 16; ++kk) {
      const float4 a4 = *(const float4*)&As[kk][ty4];
      const float4 b4 = *(const float4*)&Bs[kk][tx4];
      acc[0][0] = fmaf(a4.x, b4.x, acc[0][0]);
      acc[0][1] = fmaf(a4.x, b4.y, acc[0][1]);
      acc[0][2] = fmaf(a4.x, b4.z, acc[0][2]);
      acc[0][3] = fmaf(a4.x, b4.w, acc[0][3]);
      acc[1][0] = fmaf(a4.y, b4.x, acc[1][0]);
      acc[1][1] = fmaf(a4.y, b4.y, acc[1][1]);
      acc[1][2] = fmaf(a4.y, b4.z, acc[1][2]);
      acc[1][3] = fmaf(a4.y, b4.w, acc[1][3]);
      acc[2][0] = fmaf(a4.z, b4.x, acc[2][0]);
      acc[2][1] = fmaf(a4.z, b4.y, acc[2][1]);
      acc[2][2] = fmaf(a4.z, b4.z, acc[2][2]);
      acc[2][3] = fmaf(a4.z, b4.w, acc[2][3]);
      acc[3][0] = fmaf(a4.w, b4.x, acc[3][0]);
      acc[3][1] = fmaf(a4.w, b4.y, acc[3][1]);
      acc[3][2] = fmaf(a4.w, b4.z, acc[3][2]);
      acc[3][3] = fmaf(a4.w, b4.w, acc[3][3]);
    }
  }
#pragma unroll
  for (int i2 = 0; i2 < 4; ++i2) {
    float4 o;
    o.x = acc[i2][0]; o.y = acc[i2][1]; o.z = acc[i2][2]; o.w = acc[i2][3];
    *(float4*)&C[(row0 + ty4 + i2) * HD + col0 + tx4] = o;
  }
}

// K2: sl[b,h,i] = g[b,i,h,:].a_l ; sr[b,h,j] = g[b,j,h,:].a_r  (one wave per (b,n,h))
__global__ __launch_bounds__(256) void k_scores(const float* __restrict__ g,
                                                const float* __restrict__ aw,
                                                float* __restrict__ sl,
                                                float* __restrict__ sr) {
  const int wv = blockIdx.x * 4 + (threadIdx.x >> 6);
  const int lane = threadIdx.x & 63;
  const int h = wv & 7;
  const int row = wv >> 3;  // b*N + n
  const float x = g[row * HD + h * DH + lane];
  const float s1 = wave_sum(x * aw[lane]);
  const float s2 = wave_sum(x * aw[DH + lane]);
  if (lane == 0) {
    const int b = row >> 11, n = row & (N_ - 1);
    sl[(b * H_ + h) * N_ + n] = s1;
    sr[(b * H_ + h) * N_ + n] = s2;
  }
}

// K3: bitonic sort of sr per (b,h), ascending, with original-index payload
__global__ __launch_bounds__(1024) void k_sort(const float* __restrict__ sr,
                                               float* __restrict__ sv,
                                               int* __restrict__ si) {
  __shared__ float v[2048];
  __shared__ int ix[2048];
  const int t = threadIdx.x;
  const int base = blockIdx.x * N_;
  v[t] = sr[base + t];
  v[t + 1024] = sr[base + t + 1024];
  ix[t] = t;
  ix[t + 1024] = t + 1024;
  __syncthreads();
  for (int k = 2; k <= 2048; k <<= 1) {
    for (int j = k >> 1; j > 0; j >>= 1) {
      const int i = ((t & ~(j - 1)) << 1) | (t & (j - 1));
      const int p = i | j;
      const bool up = ((i & k) == 0);
      const float a = v[i], b2 = v[p];
      if ((a > b2) == up) {
        v[i] = b2; v[p] = a;
        const int tmp = ix[i]; ix[i] = ix[p]; ix[p] = tmp;
      }
      __syncthreads();
    }
  }
  sv[base + t] = v[t];
  sv[base + t + 1024] = v[t + 1024];
  si[base + t] = ix[t];
  si[base + t + 1024] = ix[t + 1024];
}

// K4: per (b,h,chunk): element-granular exclusive prefixes of w*g (P1/P2) and
// of the scalar weights (Zpe1/Zpe2, via wave shfl_up scan), plus chunk totals.
__global__ __launch_bounds__(64) void k_chunks(const float* __restrict__ g,
                                               const float* __restrict__ sv,
                                               const int* __restrict__ si,
                                               float* __restrict__ P1,
                                               float* __restrict__ P2,
                                               float* __restrict__ Zpe1,
                                               float* __restrict__ Zpe2,
                                               float* __restrict__ C1,
                                               float* __restrict__ C2,
                                               float* __restrict__ Zc1,
                                               float* __restrict__ Zc2) {
  const int bh = blockIdx.x >> 5;
  const int c = blockIdx.x & 31;
  const int b = bh >> 3, h = bh & 7;
  const int lane = threadIdx.x;
  const int base = bh * N_;
  const int t = c * CH + lane;
  const float m = sv[base + N_ - 1];
  const float val = sv[base + t];
  const float e1 = __expf(val - m);
  const float e2 = __expf(SLOPE * (val - m));
  const int jv = si[base + t];
  // exclusive wave scan of e1,e2 over sorted positions within the chunk
  float s1 = e1, s2 = e2;
#pragma unroll
  for (int off = 1; off < 64; off <<= 1) {
    const float o1 = __shfl_up(s1, off, 64);
    const float o2 = __shfl_up(s2, off, 64);
    if (lane >= off) { s1 += o1; s2 += o2; }
  }
  Zpe1[base + t] = s1 - e1;
  Zpe2[base + t] = s2 - e2;
  if (lane == 63) { Zc1[blockIdx.x] = s1; Zc2[blockIdx.x] = s2; }
  float acc1 = 0.f, acc2 = 0.f;
#pragma unroll 8
  for (int u = 0; u < CH; ++u) {
    P1[(base + c * CH + u) * 64 + lane] = acc1;  // exclusive intra-chunk prefix
    P2[(base + c * CH + u) * 64 + lane] = acc2;
    const float wa = __shfl(e1, u, 64);
    const float wb = __shfl(e2, u, 64);
    const int j = __shfl(jv, u, 64);
    const float gv = g[(b * N_ + j) * HD + h * DH + lane];
    acc1 = fmaf(wa, gv, acc1);
    acc2 = fmaf(wb, gv, acc2);
  }
  C1[blockIdx.x * 64 + lane] = acc1;
  C2[blockIdx.x * 64 + lane] = acc2;
}

// K5: exclusive scan of chunk sums (33 entries incl. total), per (b,h)
__global__ __launch_bounds__(64) void k_scan(const float* __restrict__ C1,
                                             const float* __restrict__ C2,
                                             const float* __restrict__ Zc1,
                                             const float* __restrict__ Zc2,
                                             float* __restrict__ U1,
                                             float* __restrict__ U2,
                                             float* __restrict__ Zb1,
                                             float* __restrict__ Zb2) {
  const int bh = blockIdx.x;
  const int d = threadIdx.x;
  float r1 = 0.f, r2 = 0.f;
  for (int c = 0; c < NCHUNK; ++c) {
    U1[(bh * 33 + c) * 64 + d] = r1;
    U2[(bh * 33 + c) * 64 + d] = r2;
    r1 += C1[(bh * 32 + c) * 64 + d];
    r2 += C2[(bh * 32 + c) * 64 + d];
  }
  U1[(bh * 33 + 32) * 64 + d] = r1;
  U2[(bh * 33 + 32) * 64 + d] = r2;
  if (d == 0) {
    float z1 = 0.f, z2 = 0.f;
    for (int c = 0; c < NCHUNK; ++c) {
      Zb1[bh * 33 + c] = z1;
      Zb2[bh * 33 + c] = z2;
      z1 += Zc1[bh * 32 + c];
      z2 += Zc2[bh * 32 + c];
    }
    Zb1[bh * 33 + 32] = z1;
    Zb2[bh * 33 + 32] = z2;
  }
}

// K6: per row i: 2-step 64-ary ballot search for split p, then pure prefix reads
__global__ __launch_bounds__(256) void k_out(const float* __restrict__ sl,
                                             const float* __restrict__ sv,
                                             const float* __restrict__ P1,
                                             const float* __restrict__ P2,
                                             const float* __restrict__ Zpe1,
                                             const float* __restrict__ Zpe2,
                                             const float* __restrict__ U1,
                                             const float* __restrict__ U2,
                                             const float* __restrict__ Zb1,
                                             const float* __restrict__ Zb2,
                                             float* __restrict__ out) {
  const int wv = blockIdx.x * 4 + (threadIdx.x >> 6);
  const int d = threadIdx.x & 63;
  const int h = wv & 7;
  const int row = wv >> 3;
  const int b = row >> 11;
  const int i = row & (N_ - 1);
  const int bh = b * H_ + h;
  const int base = bh * N_;
  const float sli = sl[base + i];
  const float m = sv[base + N_ - 1];
  const float th = -sli;
  // p = first sorted index with sv >= th; 64-ary search: 2 probe rounds
  const unsigned long long m1 = __ballot(sv[base + d * 32 + 31] < th);
  const int nb = __popcll(m1);  // # of 32-blocks entirely below th
  int p;
  if (nb >= 64) {
    p = N_;
  } else {
    const unsigned long long m2 =
        __ballot((d < 32) && (sv[base + nb * 32 + (d & 31)] < th));
    p = nb * 32 + __popcll(m2);
  }
  const float slm = sli + m;
  const float M = slm >= 0.f ? slm : SLOPE * slm;  // row max of e
  const float c1 = __expf(slm - M);                // positive-branch scale (<=1)
  const float c2 = __expf(SLOPE * slm - M);        // negative-branch scale (<=1)
  const int c = p >> 6;
  const float tot1 = U1[(bh * 33 + 32) * 64 + d];
  const float b1 = U1[(bh * 33 + c) * 64 + d];
  const float b2 = U2[(bh * 33 + c) * 64 + d];
  const float zt1 = Zb1[bh * 33 + 32];
  const float zb1 = Zb1[bh * 33 + c];
  const float zb2 = Zb2[bh * 33 + c];
  float p1 = 0.f, p2 = 0.f, zp1 = 0.f, zp2 = 0.f;
  if (p < N_) {
    p1 = P1[(base + p) * 64 + d];
    p2 = P2[(base + p) * 64 + d];
    zp1 = Zpe1[base + p];
    zp2 = Zpe2[base + p];
  }
  const float S1 = tot1 - b1 - p1;  // suffix vector sum (positive set)
  const float P2v = b2 + p2;        // prefix vector sum (negative set)
  const float Z = c1 * (zt1 - zb1 - zp1) + c2 * (zb2 + zp2);  // Z >= 1 always
  out[row * HD + h * DH + d] = (c1 * S1 + c2 * P2v) / Z;
}

extern "C" void kernel_launch(void* const* d_in, const int* in_sizes, int n_in,
                              void* d_out, int out_size, void* d_ws, size_t ws_size,
                              hipStream_t stream) {
  const float* f = (const float*)d_in[0];
  // d_in[1] = adj_mat (all ones, unused by reference math)
  const float* W = (const float*)d_in[2];
  const float* aw = (const float*)d_in[3];
  float* out = (float*)d_out;

  float* g = (float*)d_ws;                 // 2*2048*512 = 2.10M floats
  float* sl = g + B_ * N_ * HD;            // 32768 each, layout [(b*H+h)*N + n]
  float* sr = sl + B_ * N_ * H_;
  float* sv = sr + B_ * N_ * H_;
  int* si = (int*)(sv + B_ * N_ * H_);
  float* P1 = (float*)(si + B_ * N_ * H_); // 16*2048*64 = 2.10M floats each
  float* P2 = P1 + B_ * H_ * N_ * 64;
  float* Zpe1 = P2 + B_ * H_ * N_ * 64;    // 32768 each
  float* Zpe2 = Zpe1 + B_ * N_ * H_;
  float* U1 = Zpe2 + B_ * N_ * H_;         // 16*33*64 exclusive bases + total
  float* U2 = U1 + 16 * 33 * 64;
  float* Zb1 = U2 + 16 * 33 * 64;          // 16*33
  float* Zb2 = Zb1 + 16 * 33;
  float* C1 = Zb2 + 16 * 33;               // 16*32*64 chunk sums
  float* C2 = C1 + 16 * 32 * 64;
  float* Zc1 = C2 + 16 * 32 * 64;          // 16*32
  float* Zc2 = Zc1 + 16 * 32;

  hipLaunchKernelGGL(k_gemm, dim3(HD / 64, (B_ * N_) / 64), dim3(256), 0, stream, f, W, g);
  hipLaunchKernelGGL(k_scores, dim3(B_ * N_ * H_ / 4), dim3(256), 0, stream, g, aw, sl, sr);
  hipLaunchKernelGGL(k_sort, dim3(B_ * H_), dim3(1024), 0, stream, sr, sv, si);
  hipLaunchKernelGGL(k_chunks, dim3(B_ * H_ * NCHUNK), dim3(64), 0, stream, g, sv, si,
                     P1, P2, Zpe1, Zpe2, C1, C2, Zc1, Zc2);
  hipLaunchKernelGGL(k_scan, dim3(B_ * H_), dim3(64), 0, stream, C1, C2, Zc1, Zc2, U1, U2, Zb1, Zb2);
  hipLaunchKernelGGL(k_out, dim3(B_ * N_ * H_ / 4), dim3(256), 0, stream,
                     sl, sv, P1, P2, Zpe1, Zpe2, U1, U2, Zb1, Zb2, out);
}

// Round 3
// 79.374 us; speedup vs baseline: 2.0854x; 1.1766x over previous
//
#include <hip/hip_runtime.h>
#include <hip/hip_bf16.h>

#define B_ 2
#define N_ 2048
#define FIN 512
#define H_ 8
#define DH 64
#define HD 512 /* H_*DH */
#define SLOPE 0.2f
#define NCHUNK 32
#define CH 64

typedef __attribute__((ext_vector_type(8))) short short8;
typedef __attribute__((ext_vector_type(4))) float f32x4;
typedef unsigned short ushort_t;

__device__ __forceinline__ float wave_sum(float v) {
#pragma unroll
  for (int off = 32; off > 0; off >>= 1) v += __shfl_xor(v, off, 64);
  return v;
}

#define GLOAD_LDS(gp, lp)                                                   \
  __builtin_amdgcn_global_load_lds(                                         \
      (const __attribute__((address_space(1))) void*)(gp),                  \
      (__attribute__((address_space(3))) void*)(lp), 16, 0, 0)

// K0a: split f (fp32) into bf16 hi/lo arrays
__global__ __launch_bounds__(256) void k_cvt_f(const float* __restrict__ f,
                                               ushort_t* __restrict__ fh,
                                               ushort_t* __restrict__ fl) {
  const int i = (blockIdx.x * 256 + threadIdx.x) * 4;
  const float4 v = *(const float4*)(f + i);
  const float vv[4] = {v.x, v.y, v.z, v.w};
  ushort_t hh[4], ll[4];
#pragma unroll
  for (int j = 0; j < 4; ++j) {
    const float x = vv[j];
    const __hip_bfloat16 hb = __float2bfloat16(x);
    const float hf = __bfloat162float(hb);
    const __hip_bfloat16 lb = __float2bfloat16(x - hf);
    hh[j] = *(const ushort_t*)&hb;
    ll[j] = *(const ushort_t*)&lb;
  }
  ushort4 ho, lo;
  ho.x = hh[0]; ho.y = hh[1]; ho.z = hh[2]; ho.w = hh[3];
  lo.x = ll[0]; lo.y = ll[1]; lo.z = ll[2]; lo.w = ll[3];
  *(ushort4*)(fh + i) = ho;
  *(ushort4*)(fl + i) = lo;
}

// K0b: transpose W [k][n] -> Wt [n][k], split into bf16 hi/lo
__global__ __launch_bounds__(256) void k_cvt_w(const float* __restrict__ W,
                                               ushort_t* __restrict__ Bth,
                                               ushort_t* __restrict__ Btl) {
  __shared__ float T[64][65];
  const int k0 = blockIdx.x * 64;
  const int n0 = blockIdx.y * 64;
  const int tx = threadIdx.x & 63, ty = threadIdx.x >> 6;
#pragma unroll
  for (int p = 0; p < 16; ++p) {
    const int kr = p * 4 + ty;
    T[kr][tx] = W[(k0 + kr) * HD + n0 + tx];
  }
  __syncthreads();
#pragma unroll
  for (int p = 0; p < 16; ++p) {
    const int nr = p * 4 + ty;
    const float x = T[tx][nr];
    const __hip_bfloat16 hb = __float2bfloat16(x);
    const float hf = __bfloat162float(hb);
    const __hip_bfloat16 lb = __float2bfloat16(x - hf);
    Bth[(n0 + nr) * FIN + k0 + tx] = *(const ushort_t*)&hb;
    Btl[(n0 + nr) * FIN + k0 + tx] = *(const ushort_t*)&lb;
  }
}

// K1: g = f @ W via bf16 MFMA, split precision (ah*bh + ah*bl + al*bh).
// 64x64 tile, BK=64, 4 waves (2x2), grid (64,8). XOR-swizzled LDS
// (byte ^= (row&7)<<4) applied on the GLOBAL source (G21) + on ds_read.
__global__ __launch_bounds__(256) void k_gemm_mfma(
    const ushort_t* __restrict__ Ah, const ushort_t* __restrict__ Al,
    const ushort_t* __restrict__ Bth, const ushort_t* __restrict__ Btl,
    float* __restrict__ C) {
  __shared__ ushort_t lAh[64 * 64], lAl[64 * 64], lBh[64 * 64], lBl[64 * 64];
  const int tid = threadIdx.x;
  const int lane = tid & 63;
  const int wave = tid >> 6;
  const int row0 = blockIdx.x * 64;
  const int col0 = blockIdx.y * 64;
  const int wm = (wave >> 1) * 32;
  const int wn = (wave & 1) * 32;
  f32x4 acc[2][2] = {};

  for (int k0 = 0; k0 < FIN; k0 += 64) {
    __syncthreads();
#pragma unroll
    for (int p = 0; p < 2; ++p) {
      const int q = p * 256 + tid;
      const int r = q >> 3, s = q & 7;
      const int gk = k0 + ((s ^ (r & 7)) << 3);
      const int lo = q * 8;  // ushort offset == q*16 bytes
      GLOAD_LDS(Ah + (row0 + r) * FIN + gk, &lAh[lo]);
      GLOAD_LDS(Al + (row0 + r) * FIN + gk, &lAl[lo]);
      GLOAD_LDS(Bth + (col0 + r) * FIN + gk, &lBh[lo]);
      GLOAD_LDS(Btl + (col0 + r) * FIN + gk, &lBl[lo]);
    }
    __syncthreads();
#pragma unroll
    for (int kk = 0; kk < 2; ++kk) {
      short8 a_h[2], a_l[2], b_h[2], b_l[2];
#pragma unroll
      for (int fm = 0; fm < 2; ++fm) {
        const int row = wm + fm * 16 + (lane & 15);
        const int kbyte = kk * 64 + ((lane >> 4) << 4);
        const int off = (row * 128 + (kbyte ^ ((row & 7) << 4))) >> 1;
        a_h[fm] = *(const short8*)&lAh[off];
        a_l[fm] = *(const short8*)&lAl[off];
      }
#pragma unroll
      for (int fn = 0; fn < 2; ++fn) {
        const int nn = wn + fn * 16 + (lane & 15);
        const int kbyte = kk * 64 + ((lane >> 4) << 4);
        const int off = (nn * 128 + (kbyte ^ ((nn & 7) << 4))) >> 1;
        b_h[fn] = *(const short8*)&lBh[off];
        b_l[fn] = *(const short8*)&lBl[off];
      }
#pragma unroll
      for (int fm = 0; fm < 2; ++fm)
#pragma unroll
        for (int fn = 0; fn < 2; ++fn) {
          acc[fm][fn] = __builtin_amdgcn_mfma_f32_16x16x32_bf16(
              a_h[fm], b_h[fn], acc[fm][fn], 0, 0, 0);
          acc[fm][fn] = __builtin_amdgcn_mfma_f32_16x16x32_bf16(
              a_h[fm], b_l[fn], acc[fm][fn], 0, 0, 0);
          acc[fm][fn] = __builtin_amdgcn_mfma_f32_16x16x32_bf16(
              a_l[fm], b_h[fn], acc[fm][fn], 0, 0, 0);
        }
    }
  }
#pragma unroll
  for (int fm = 0; fm < 2; ++fm)
#pragma unroll
    for (int fn = 0; fn < 2; ++fn)
#pragma unroll
      for (int r = 0; r < 4; ++r) {
        const int row = row0 + wm + fm * 16 + ((lane >> 4) << 2) + r;
        const int col = col0 + wn + fn * 16 + (lane & 15);
        C[row * HD + col] = acc[fm][fn][r];
      }
}

// K2: sl[b,h,i] = g[b,i,h,:].a_l ; sr[b,h,j] = g[b,j,h,:].a_r  (one wave per (b,n,h))
__global__ __launch_bounds__(256) void k_scores(const float* __restrict__ g,
                                                const float* __restrict__ aw,
                                                float* __restrict__ sl,
                                                float* __restrict__ sr) {
  const int wv = blockIdx.x * 4 + (threadIdx.x >> 6);
  const int lane = threadIdx.x & 63;
  const int h = wv & 7;
  const int row = wv >> 3;  // b*N + n
  const float x = g[row * HD + h * DH + lane];
  const float s1 = wave_sum(x * aw[lane]);
  const float s2 = wave_sum(x * aw[DH + lane]);
  if (lane == 0) {
    const int b = row >> 11, n = row & (N_ - 1);
    sl[(b * H_ + h) * N_ + n] = s1;
    sr[(b * H_ + h) * N_ + n] = s2;
  }
}

// K3: bitonic sort of sr per (b,h), ascending, with original-index payload
__global__ __launch_bounds__(1024) void k_sort(const float* __restrict__ sr,
                                               float* __restrict__ sv,
                                               int* __restrict__ si) {
  __shared__ float v[2048];
  __shared__ int ix[2048];
  const int t = threadIdx.x;
  const int base = blockIdx.x * N_;
  v[t] = sr[base + t];
  v[t + 1024] = sr[base + t + 1024];
  ix[t] = t;
  ix[t + 1024] = t + 1024;
  __syncthreads();
  for (int k = 2; k <= 2048; k <<= 1) {
    for (int j = k >> 1; j > 0; j >>= 1) {
      const int i = ((t & ~(j - 1)) << 1) | (t & (j - 1));
      const int p = i | j;
      const bool up = ((i & k) == 0);
      const float a = v[i], b2 = v[p];
      if ((a > b2) == up) {
        v[i] = b2; v[p] = a;
        const int tmp = ix[i]; ix[i] = ix[p]; ix[p] = tmp;
      }
      __syncthreads();
    }
  }
  sv[base + t] = v[t];
  sv[base + t + 1024] = v[t + 1024];
  si[base + t] = ix[t];
  si[base + t + 1024] = ix[t + 1024];
}

// K4: per (b,h,chunk): element-granular exclusive prefixes of w*g (P1/P2) and
// of the scalar weights (Zpe1/Zpe2, via wave shfl_up scan), plus chunk totals.
__global__ __launch_bounds__(64) void k_chunks(const float* __restrict__ g,
                                               const float* __restrict__ sv,
                                               const int* __restrict__ si,
                                               float* __restrict__ P1,
                                               float* __restrict__ P2,
                                               float* __restrict__ Zpe1,
                                               float* __restrict__ Zpe2,
                                               float* __restrict__ C1,
                                               float* __restrict__ C2,
                                               float* __restrict__ Zc1,
                                               float* __restrict__ Zc2) {
  const int bh = blockIdx.x >> 5;
  const int c = blockIdx.x & 31;
  const int b = bh >> 3, h = bh & 7;
  const int lane = threadIdx.x;
  const int base = bh * N_;
  const int t = c * CH + lane;
  const float m = sv[base + N_ - 1];
  const float val = sv[base + t];
  const float e1 = __expf(val - m);
  const float e2 = __expf(SLOPE * (val - m));
  const int jv = si[base + t];
  float s1 = e1, s2 = e2;
#pragma unroll
  for (int off = 1; off < 64; off <<= 1) {
    const float o1 = __shfl_up(s1, off, 64);
    const float o2 = __shfl_up(s2, off, 64);
    if (lane >= off) { s1 += o1; s2 += o2; }
  }
  Zpe1[base + t] = s1 - e1;
  Zpe2[base + t] = s2 - e2;
  if (lane == 63) { Zc1[blockIdx.x] = s1; Zc2[blockIdx.x] = s2; }
  float acc1 = 0.f, acc2 = 0.f;
#pragma unroll 8
  for (int u = 0; u < CH; ++u) {
    P1[(base + c * CH + u) * 64 + lane] = acc1;  // exclusive intra-chunk prefix
    P2[(base + c * CH + u) * 64 + lane] = acc2;
    const float wa = __shfl(e1, u, 64);
    const float wb = __shfl(e2, u, 64);
    const int j = __shfl(jv, u, 64);
    const float gv = g[(b * N_ + j) * HD + h * DH + lane];
    acc1 = fmaf(wa, gv, acc1);
    acc2 = fmaf(wb, gv, acc2);
  }
  C1[blockIdx.x * 64 + lane] = acc1;
  C2[blockIdx.x * 64 + lane] = acc2;
}

// K5: exclusive scan of chunk sums (33 entries incl. total), per (b,h)
__global__ __launch_bounds__(64) void k_scan(const float* __restrict__ C1,
                                             const float* __restrict__ C2,
                                             const float* __restrict__ Zc1,
                                             const float* __restrict__ Zc2,
                                             float* __restrict__ U1,
                                             float* __restrict__ U2,
                                             float* __restrict__ Zb1,
                                             float* __restrict__ Zb2) {
  const int bh = blockIdx.x;
  const int d = threadIdx.x;
  float r1 = 0.f, r2 = 0.f;
  for (int c = 0; c < NCHUNK; ++c) {
    U1[(bh * 33 + c) * 64 + d] = r1;
    U2[(bh * 33 + c) * 64 + d] = r2;
    r1 += C1[(bh * 32 + c) * 64 + d];
    r2 += C2[(bh * 32 + c) * 64 + d];
  }
  U1[(bh * 33 + 32) * 64 + d] = r1;
  U2[(bh * 33 + 32) * 64 + d] = r2;
  if (d == 0) {
    float z1 = 0.f, z2 = 0.f;
    for (int c = 0; c < NCHUNK; ++c) {
      Zb1[bh * 33 + c] = z1;
      Zb2[bh * 33 + c] = z2;
      z1 += Zc1[bh * 32 + c];
      z2 += Zc2[bh * 32 + c];
    }
    Zb1[bh * 33 + 32] = z1;
    Zb2[bh * 33 + 32] = z2;
  }
}

// K6: per row i: 2-step 64-ary ballot search for split p, then pure prefix reads
__global__ __launch_bounds__(256) void k_out(const float* __restrict__ sl,
                                             const float* __restrict__ sv,
                                             const float* __restrict__ P1,
                                             const float* __restrict__ P2,
                                             const float* __restrict__ Zpe1,
                                             const float* __restrict__ Zpe2,
                                             const float* __restrict__ U1,
                                             const float* __restrict__ U2,
                                             const float* __restrict__ Zb1,
                                             const float* __restrict__ Zb2,
                                             float* __restrict__ out) {
  const int wv = blockIdx.x * 4 + (threadIdx.x >> 6);
  const int d = threadIdx.x & 63;
  const int h = wv & 7;
  const int row = wv >> 3;
  const int b = row >> 11;
  const int i = row & (N_ - 1);
  const int bh = b * H_ + h;
  const int base = bh * N_;
  const float sli = sl[base + i];
  const float m = sv[base + N_ - 1];
  const float th = -sli;
  const unsigned long long m1 = __ballot(sv[base + d * 32 + 31] < th);
  const int nb = __popcll(m1);
  int p;
  if (nb >= 64) {
    p = N_;
  } else {
    const unsigned long long m2 =
        __ballot((d < 32) && (sv[base + nb * 32 + (d & 31)] < th));
    p = nb * 32 + __popcll(m2);
  }
  const float slm = sli + m;
  const float M = slm >= 0.f ? slm : SLOPE * slm;
  const float c1 = __expf(slm - M);
  const float c2 = __expf(SLOPE * slm - M);
  const int c = p >> 6;
  const float tot1 = U1[(bh * 33 + 32) * 64 + d];
  const float b1 = U1[(bh * 33 + c) * 64 + d];
  const float b2 = U2[(bh * 33 + c) * 64 + d];
  const float zt1 = Zb1[bh * 33 + 32];
  const float zb1 = Zb1[bh * 33 + c];
  const float zb2 = Zb2[bh * 33 + c];
  float p1 = 0.f, p2 = 0.f, zp1 = 0.f, zp2 = 0.f;
  if (p < N_) {
    p1 = P1[(base + p) * 64 + d];
    p2 = P2[(base + p) * 64 + d];
    zp1 = Zpe1[base + p];
    zp2 = Zpe2[base + p];
  }
  const float S1 = tot1 - b1 - p1;
  const float P2v = b2 + p2;
  const float Z = c1 * (zt1 - zb1 - zp1) + c2 * (zb2 + zp2);
  out[row * HD + h * DH + d] = (c1 * S1 + c2 * P2v) / Z;
}

extern "C" void kernel_launch(void* const* d_in, const int* in_sizes, int n_in,
                              void* d_out, int out_size, void* d_ws, size_t ws_size,
                              hipStream_t stream) {
  const float* f = (const float*)d_in[0];
  // d_in[1] = adj_mat (all ones, unused by reference math)
  const float* W = (const float*)d_in[2];
  const float* aw = (const float*)d_in[3];
  float* out = (float*)d_out;

  float* g = (float*)d_ws;                 // 2*2048*512 = 2.10M floats
  float* sl = g + B_ * N_ * HD;            // 32768 each, layout [(b*H+h)*N + n]
  float* sr = sl + B_ * N_ * H_;
  float* sv = sr + B_ * N_ * H_;
  int* si = (int*)(sv + B_ * N_ * H_);
  float* P1 = (float*)(si + B_ * N_ * H_); // 16*2048*64 = 2.10M floats each
  float* P2 = P1 + B_ * H_ * N_ * 64;
  float* Zpe1 = P2 + B_ * H_ * N_ * 64;    // 32768 each
  float* Zpe2 = Zpe1 + B_ * N_ * H_;
  float* U1 = Zpe2 + B_ * N_ * H_;         // 16*33*64 exclusive bases + total
  float* U2 = U1 + 16 * 33 * 64;
  float* Zb1 = U2 + 16 * 33 * 64;          // 16*33
  float* Zb2 = Zb1 + 16 * 33;
  float* C1 = Zb2 + 16 * 33;               // 16*32*64 chunk sums
  float* C2 = C1 + 16 * 32 * 64;
  float* Zc1 = C2 + 16 * 32 * 64;          // 16*32
  float* Zc2 = Zc1 + 16 * 32;

  // bf16 hi/lo split staging areas: alias P1/P2 (dead until k_chunks runs,
  // which is after the GEMM completes). fh+fl = 8.39 MB == sizeof(P1).
  ushort_t* fh = (ushort_t*)P1;            // 4096*512 bf16
  ushort_t* fl = fh + 4096 * FIN;
  ushort_t* Bth = (ushort_t*)P2;           // Wt [n][k] hi, 512*512
  ushort_t* Btl = Bth + HD * FIN;

  hipLaunchKernelGGL(k_cvt_f, dim3((B_ * N_ * FIN) / 1024), dim3(256), 0, stream, f, fh, fl);
  hipLaunchKernelGGL(k_cvt_w, dim3(FIN / 64, HD / 64), dim3(256), 0, stream, W, Bth, Btl);
  hipLaunchKernelGGL(k_gemm_mfma, dim3((B_ * N_) / 64, HD / 64), dim3(256), 0, stream,
                     fh, fl, Bth, Btl, g);
  hipLaunchKernelGGL(k_scores, dim3(B_ * N_ * H_ / 4), dim3(256), 0, stream, g, aw, sl, sr);
  hipLaunchKernelGGL(k_sort, dim3(B_ * H_), dim3(1024), 0, stream, sr, sv, si);
  hipLaunchKernelGGL(k_chunks, dim3(B_ * H_ * NCHUNK), dim3(64), 0, stream, g, sv, si,
                     P1, P2, Zpe1, Zpe2, C1, C2, Zc1, Zc2);
  hipLaunchKernelGGL(k_scan, dim3(B_ * H_), dim3(64), 0, stream, C1, C2, Zc1, Zc2, U1, U2, Zb1, Zb2);
  hipLaunchKernelGGL(k_out, dim3(B_ * N_ * H_ / 4), dim3(256), 0, stream,
                     sl, sv, P1, P2, Zpe1, Zpe2, U1, U2, Zb1, Zb2, out);
}

// Round 4
// 74.278 us; speedup vs baseline: 2.2285x; 1.0686x over previous
//
#include <hip/hip_runtime.h>
#include <hip/hip_bf16.h>

#define B_ 2
#define N_ 2048
#define FIN 512
#define H_ 8
#define DH 64
#define HD 512 /* H_*DH */
#define SLOPE 0.2f
#define NCHUNK 32
#define CH 64

typedef __attribute__((ext_vector_type(8))) short short8;
typedef __attribute__((ext_vector_type(4))) float f32x4;
typedef unsigned short ushort_t;

__device__ __forceinline__ float wave_sum(float v) {
#pragma unroll
  for (int off = 32; off > 0; off >>= 1) v += __shfl_xor(v, off, 64);
  return v;
}

#define GLOAD_LDS(gp, lp)                                                   \
  __builtin_amdgcn_global_load_lds(                                         \
      (const __attribute__((address_space(1))) void*)(gp),                  \
      (__attribute__((address_space(3))) void*)(lp), 16, 0, 0)

// K0a: split f (fp32) into bf16 hi/lo arrays
__global__ __launch_bounds__(256) void k_cvt_f(const float* __restrict__ f,
                                               ushort_t* __restrict__ fh,
                                               ushort_t* __restrict__ fl) {
  const int i = (blockIdx.x * 256 + threadIdx.x) * 4;
  const float4 v = *(const float4*)(f + i);
  const float vv[4] = {v.x, v.y, v.z, v.w};
  ushort_t hh[4], ll[4];
#pragma unroll
  for (int j = 0; j < 4; ++j) {
    const float x = vv[j];
    const __hip_bfloat16 hb = __float2bfloat16(x);
    const float hf = __bfloat162float(hb);
    const __hip_bfloat16 lb = __float2bfloat16(x - hf);
    hh[j] = *(const ushort_t*)&hb;
    ll[j] = *(const ushort_t*)&lb;
  }
  ushort4 ho, lo;
  ho.x = hh[0]; ho.y = hh[1]; ho.z = hh[2]; ho.w = hh[3];
  lo.x = ll[0]; lo.y = ll[1]; lo.z = ll[2]; lo.w = ll[3];
  *(ushort4*)(fh + i) = ho;
  *(ushort4*)(fl + i) = lo;
}

// K0b: transpose W [k][n] -> Wt [n][k], split into bf16 hi/lo
__global__ __launch_bounds__(256) void k_cvt_w(const float* __restrict__ W,
                                               ushort_t* __restrict__ Bth,
                                               ushort_t* __restrict__ Btl) {
  __shared__ float T[64][65];
  const int k0 = blockIdx.x * 64;
  const int n0 = blockIdx.y * 64;
  const int tx = threadIdx.x & 63, ty = threadIdx.x >> 6;
#pragma unroll
  for (int p = 0; p < 16; ++p) {
    const int kr = p * 4 + ty;
    T[kr][tx] = W[(k0 + kr) * HD + n0 + tx];
  }
  __syncthreads();
#pragma unroll
  for (int p = 0; p < 16; ++p) {
    const int nr = p * 4 + ty;
    const float x = T[tx][nr];
    const __hip_bfloat16 hb = __float2bfloat16(x);
    const float hf = __bfloat162float(hb);
    const __hip_bfloat16 lb = __float2bfloat16(x - hf);
    Bth[(n0 + nr) * FIN + k0 + tx] = *(const ushort_t*)&hb;
    Btl[(n0 + nr) * FIN + k0 + tx] = *(const ushort_t*)&lb;
  }
}

// K1: g = f @ W via bf16 MFMA split precision (ah*bh + ah*bl + al*bh).
// 64x64 tile, BK=64, 4 waves, 2-phase double-buffered LDS prefetch (T3-min).
// Fused epilogue computes sl/sr (per-row dots with attn_w) — col tile == head.
__global__ __launch_bounds__(256) void k_gemm_mfma(
    const ushort_t* __restrict__ Ah, const ushort_t* __restrict__ Al,
    const ushort_t* __restrict__ Bth, const ushort_t* __restrict__ Btl,
    const float* __restrict__ aw, float* __restrict__ C,
    float* __restrict__ sl, float* __restrict__ sr) {
  __shared__ ushort_t lA[2][2][64 * 64];  // [buf][hi/lo]
  __shared__ ushort_t lB[2][2][64 * 64];
  __shared__ float slp[2][64], srp[2][64];
  const int tid = threadIdx.x;
  const int lane = tid & 63;
  const int wave = tid >> 6;
  const int row0 = blockIdx.x * 64;
  const int col0 = blockIdx.y * 64;
  const int wm = (wave >> 1) * 32;
  const int wn = (wave & 1) * 32;
  f32x4 acc[2][2] = {};

#define STAGE(buf, k0)                                                      \
  {                                                                         \
    _Pragma("unroll") for (int p = 0; p < 2; ++p) {                         \
      const int q = p * 256 + tid;                                          \
      const int r = q >> 3, s = q & 7;                                      \
      const int gk = (k0) + ((s ^ (r & 7)) << 3);                           \
      const int lo_ = q * 8;                                                \
      GLOAD_LDS(Ah + (row0 + r) * FIN + gk, &lA[buf][0][lo_]);              \
      GLOAD_LDS(Al + (row0 + r) * FIN + gk, &lA[buf][1][lo_]);              \
      GLOAD_LDS(Bth + (col0 + r) * FIN + gk, &lB[buf][0][lo_]);             \
      GLOAD_LDS(Btl + (col0 + r) * FIN + gk, &lB[buf][1][lo_]);             \
    }                                                                       \
  }

  STAGE(0, 0);
  __syncthreads();  // implicit vmcnt(0) drain
  int cur = 0;
  for (int t = 0; t < 8; ++t) {
    if (t + 1 < 8) STAGE(cur ^ 1, (t + 1) * 64);  // prefetch next tile
#pragma unroll
    for (int kk = 0; kk < 2; ++kk) {
      short8 a_h[2], a_l[2], b_h[2], b_l[2];
      const int kbyte = kk * 64 + ((lane >> 4) << 4);
#pragma unroll
      for (int fm = 0; fm < 2; ++fm) {
        const int row = wm + fm * 16 + (lane & 15);
        const int off = (row * 128 + (kbyte ^ ((row & 7) << 4))) >> 1;
        a_h[fm] = *(const short8*)&lA[cur][0][off];
        a_l[fm] = *(const short8*)&lA[cur][1][off];
      }
#pragma unroll
      for (int fn = 0; fn < 2; ++fn) {
        const int nn = wn + fn * 16 + (lane & 15);
        const int off = (nn * 128 + (kbyte ^ ((nn & 7) << 4))) >> 1;
        b_h[fn] = *(const short8*)&lB[cur][0][off];
        b_l[fn] = *(const short8*)&lB[cur][1][off];
      }
#pragma unroll
      for (int fm = 0; fm < 2; ++fm)
#pragma unroll
        for (int fn = 0; fn < 2; ++fn) {
          acc[fm][fn] = __builtin_amdgcn_mfma_f32_16x16x32_bf16(
              a_h[fm], b_h[fn], acc[fm][fn], 0, 0, 0);
          acc[fm][fn] = __builtin_amdgcn_mfma_f32_16x16x32_bf16(
              a_h[fm], b_l[fn], acc[fm][fn], 0, 0, 0);
          acc[fm][fn] = __builtin_amdgcn_mfma_f32_16x16x32_bf16(
              a_l[fm], b_h[fn], acc[fm][fn], 0, 0, 0);
        }
    }
    __syncthreads();  // drains prefetch vmcnt + protects buf reuse
    cur ^= 1;
  }
#undef STAGE

  // C-store
#pragma unroll
  for (int fm = 0; fm < 2; ++fm)
#pragma unroll
    for (int fn = 0; fn < 2; ++fn)
#pragma unroll
      for (int r = 0; r < 4; ++r) {
        const int row = row0 + wm + fm * 16 + ((lane >> 4) << 2) + r;
        const int col = col0 + wn + fn * 16 + (lane & 15);
        C[row * HD + col] = acc[fm][fn][r];
      }

  // fused sl/sr: per-row dot of this head-tile with a_l/a_r
  const float al0 = aw[col0 % HD ? 0 : 0] * 0.f + aw[wn + (lane & 15)];  // aw[head-local col]
  const float al1 = aw[wn + 16 + (lane & 15)];
  const float ar0 = aw[DH + wn + (lane & 15)];
  const float ar1 = aw[DH + wn + 16 + (lane & 15)];
#pragma unroll
  for (int fm = 0; fm < 2; ++fm)
#pragma unroll
    for (int r = 0; r < 4; ++r) {
      float vsl = acc[fm][0][r] * al0 + acc[fm][1][r] * al1;
      float vsr = acc[fm][0][r] * ar0 + acc[fm][1][r] * ar1;
#pragma unroll
      for (int off = 1; off < 16; off <<= 1) {
        vsl += __shfl_xor(vsl, off, 64);
        vsr += __shfl_xor(vsr, off, 64);
      }
      if ((lane & 15) == 0) {
        const int rr = wm + fm * 16 + ((lane >> 4) << 2) + r;
        slp[wn >> 5][rr] = vsl;
        srp[wn >> 5][rr] = vsr;
      }
    }
  __syncthreads();
  if (tid < 64) {
    const int grow = row0 + tid;
    const int b = grow >> 11, n = grow & (N_ - 1);
    const int h = blockIdx.y;  // 64-col tile == one head
    sl[(b * H_ + h) * N_ + n] = slp[0][tid] + slp[1][tid];
    sr[(b * H_ + h) * N_ + n] = srp[0][tid] + srp[1][tid];
  }
}

// K3: bitonic sort of sr per (b,h), ascending, with original-index payload
__global__ __launch_bounds__(1024) void k_sort(const float* __restrict__ sr,
                                               float* __restrict__ sv,
                                               int* __restrict__ si) {
  __shared__ float v[2048];
  __shared__ int ix[2048];
  const int t = threadIdx.x;
  const int base = blockIdx.x * N_;
  v[t] = sr[base + t];
  v[t + 1024] = sr[base + t + 1024];
  ix[t] = t;
  ix[t + 1024] = t + 1024;
  __syncthreads();
  for (int k = 2; k <= 2048; k <<= 1) {
    for (int j = k >> 1; j > 0; j >>= 1) {
      const int i = ((t & ~(j - 1)) << 1) | (t & (j - 1));
      const int p = i | j;
      const bool up = ((i & k) == 0);
      const float a = v[i], b2 = v[p];
      if ((a > b2) == up) {
        v[i] = b2; v[p] = a;
        const int tmp = ix[i]; ix[i] = ix[p]; ix[p] = tmp;
      }
      __syncthreads();
    }
  }
  sv[base + t] = v[t];
  sv[base + t + 1024] = v[t + 1024];
  si[base + t] = ix[t];
  si[base + t + 1024] = ix[t + 1024];
}

// K3b: per row, binary-search the split point p (first sorted idx with sv >= -sl)
__global__ __launch_bounds__(256) void k_split(const float* __restrict__ sl,
                                               const float* __restrict__ sv,
                                               int* __restrict__ parr) {
  const int idx = blockIdx.x * 256 + threadIdx.x;  // bh*N + i
  const int base = idx & ~(N_ - 1);
  const float th = -sl[idx];
  int lo = 0, hi = N_;
  while (lo < hi) {
    const int mid = (lo + hi) >> 1;
    if (sv[base + mid] < th) lo = mid + 1; else hi = mid;
  }
  parr[idx] = lo;
}

// K4: per (b,h,chunk): element-granular exclusive prefixes of w*g (P1/P2) and
// of the scalar weights (Zpe1/Zpe2, via wave shfl_up scan), plus chunk totals.
__global__ __launch_bounds__(64) void k_chunks(const float* __restrict__ g,
                                               const float* __restrict__ sv,
                                               const int* __restrict__ si,
                                               float* __restrict__ P1,
                                               float* __restrict__ P2,
                                               float* __restrict__ Zpe1,
                                               float* __restrict__ Zpe2,
                                               float* __restrict__ C1,
                                               float* __restrict__ C2,
                                               float* __restrict__ Zc1,
                                               float* __restrict__ Zc2) {
  const int bh = blockIdx.x >> 5;
  const int c = blockIdx.x & 31;
  const int b = bh >> 3, h = bh & 7;
  const int lane = threadIdx.x;
  const int base = bh * N_;
  const int t = c * CH + lane;
  const float m = sv[base + N_ - 1];
  const float val = sv[base + t];
  const float e1 = __expf(val - m);
  const float e2 = __expf(SLOPE * (val - m));
  const int jv = si[base + t];
  float s1 = e1, s2 = e2;
#pragma unroll
  for (int off = 1; off < 64; off <<= 1) {
    const float o1 = __shfl_up(s1, off, 64);
    const float o2 = __shfl_up(s2, off, 64);
    if (lane >= off) { s1 += o1; s2 += o2; }
  }
  Zpe1[base + t] = s1 - e1;
  Zpe2[base + t] = s2 - e2;
  if (lane == 63) { Zc1[blockIdx.x] = s1; Zc2[blockIdx.x] = s2; }
  float acc1 = 0.f, acc2 = 0.f;
#pragma unroll 8
  for (int u = 0; u < CH; ++u) {
    P1[(base + c * CH + u) * 64 + lane] = acc1;  // exclusive intra-chunk prefix
    P2[(base + c * CH + u) * 64 + lane] = acc2;
    const float wa = __shfl(e1, u, 64);
    const float wb = __shfl(e2, u, 64);
    const int j = __shfl(jv, u, 64);
    const float gv = g[(b * N_ + j) * HD + h * DH + lane];
    acc1 = fmaf(wa, gv, acc1);
    acc2 = fmaf(wb, gv, acc2);
  }
  C1[blockIdx.x * 64 + lane] = acc1;
  C2[blockIdx.x * 64 + lane] = acc2;
}

// K5: exclusive scan of chunk sums (33 entries incl. total), per (b,h)
__global__ __launch_bounds__(64) void k_scan(const float* __restrict__ C1,
                                             const float* __restrict__ C2,
                                             const float* __restrict__ Zc1,
                                             const float* __restrict__ Zc2,
                                             float* __restrict__ U1,
                                             float* __restrict__ U2,
                                             float* __restrict__ Zb1,
                                             float* __restrict__ Zb2) {
  const int bh = blockIdx.x;
  const int d = threadIdx.x;
  float r1 = 0.f, r2 = 0.f;
  for (int c = 0; c < NCHUNK; ++c) {
    U1[(bh * 33 + c) * 64 + d] = r1;
    U2[(bh * 33 + c) * 64 + d] = r2;
    r1 += C1[(bh * 32 + c) * 64 + d];
    r2 += C2[(bh * 32 + c) * 64 + d];
  }
  U1[(bh * 33 + 32) * 64 + d] = r1;
  U2[(bh * 33 + 32) * 64 + d] = r2;
  if (d == 0) {
    float z1 = 0.f, z2 = 0.f;
    for (int c = 0; c < NCHUNK; ++c) {
      Zb1[bh * 33 + c] = z1;
      Zb2[bh * 33 + c] = z2;
      z1 += Zc1[bh * 32 + c];
      z2 += Zc2[bh * 32 + c];
    }
    Zb1[bh * 33 + 32] = z1;
    Zb2[bh * 33 + 32] = z2;
  }
}

// K6: branch-free streaming combine using precomputed split p
__global__ __launch_bounds__(256) void k_out(const float* __restrict__ sl,
                                             const float* __restrict__ sv,
                                             const int* __restrict__ parr,
                                             const float* __restrict__ P1,
                                             const float* __restrict__ P2,
                                             const float* __restrict__ Zpe1,
                                             const float* __restrict__ Zpe2,
                                             const float* __restrict__ U1,
                                             const float* __restrict__ U2,
                                             const float* __restrict__ Zb1,
                                             const float* __restrict__ Zb2,
                                             float* __restrict__ out) {
  const int wv = blockIdx.x * 4 + (threadIdx.x >> 6);
  const int d = threadIdx.x & 63;
  const int h = wv & 7;
  const int row = wv >> 3;
  const int b = row >> 11;
  const int i = row & (N_ - 1);
  const int bh = b * H_ + h;
  const int base = bh * N_;
  const float sli = sl[base + i];
  const float m = sv[base + N_ - 1];
  const int p = parr[base + i];
  const float slm = sli + m;
  const float M = slm >= 0.f ? slm : SLOPE * slm;
  const float c1 = __expf(slm - M);
  const float c2 = __expf(SLOPE * slm - M);
  const int c = p >> 6;
  const float tot1 = U1[(bh * 33 + 32) * 64 + d];
  const float b1 = U1[(bh * 33 + c) * 64 + d];
  const float b2 = U2[(bh * 33 + c) * 64 + d];
  const float zt1 = Zb1[bh * 33 + 32];
  const float zb1 = Zb1[bh * 33 + c];
  const float zb2 = Zb2[bh * 33 + c];
  float p1 = 0.f, p2 = 0.f, zp1 = 0.f, zp2 = 0.f;
  if (p < N_) {
    p1 = P1[(base + p) * 64 + d];
    p2 = P2[(base + p) * 64 + d];
    zp1 = Zpe1[base + p];
    zp2 = Zpe2[base + p];
  }
  const float S1 = tot1 - b1 - p1;
  const float P2v = b2 + p2;
  const float Z = c1 * (zt1 - zb1 - zp1) + c2 * (zb2 + zp2);
  out[row * HD + h * DH + d] = (c1 * S1 + c2 * P2v) / Z;
}

extern "C" void kernel_launch(void* const* d_in, const int* in_sizes, int n_in,
                              void* d_out, int out_size, void* d_ws, size_t ws_size,
                              hipStream_t stream) {
  const float* f = (const float*)d_in[0];
  // d_in[1] = adj_mat (all ones, unused by reference math)
  const float* W = (const float*)d_in[2];
  const float* aw = (const float*)d_in[3];
  float* out = (float*)d_out;

  float* g = (float*)d_ws;                 // 2*2048*512 = 2.10M floats
  float* sl = g + B_ * N_ * HD;            // 32768 each, layout [(b*H+h)*N + n]
  float* sr = sl + B_ * N_ * H_;
  float* sv = sr + B_ * N_ * H_;
  int* si = (int*)(sv + B_ * N_ * H_);
  float* P1 = (float*)(si + B_ * N_ * H_); // 16*2048*64 = 2.10M floats each
  float* P2 = P1 + B_ * H_ * N_ * 64;
  float* Zpe1 = P2 + B_ * H_ * N_ * 64;    // 32768 each
  float* Zpe2 = Zpe1 + B_ * N_ * H_;
  float* U1 = Zpe2 + B_ * N_ * H_;         // 16*33*64 exclusive bases + total
  float* U2 = U1 + 16 * 33 * 64;
  float* Zb1 = U2 + 16 * 33 * 64;          // 16*33
  float* Zb2 = Zb1 + 16 * 33;
  float* C1 = Zb2 + 16 * 33;               // 16*32*64 chunk sums
  float* C2 = C1 + 16 * 32 * 64;
  float* Zc1 = C2 + 16 * 32 * 64;          // 16*32
  float* Zc2 = Zc1 + 16 * 32;
  int* parr = (int*)(Zc2 + 16 * 32);       // 32768 split points

  // bf16 hi/lo staging aliases P1/P2 (dead until k_chunks, after GEMM).
  ushort_t* fh = (ushort_t*)P1;            // 4096*512 bf16
  ushort_t* fl = fh + 4096 * FIN;
  ushort_t* Bth = (ushort_t*)P2;           // Wt [n][k] hi, 512*512
  ushort_t* Btl = Bth + HD * FIN;

  hipLaunchKernelGGL(k_cvt_f, dim3((B_ * N_ * FIN) / 1024), dim3(256), 0, stream, f, fh, fl);
  hipLaunchKernelGGL(k_cvt_w, dim3(FIN / 64, HD / 64), dim3(256), 0, stream, W, Bth, Btl);
  hipLaunchKernelGGL(k_gemm_mfma, dim3((B_ * N_) / 64, HD / 64), dim3(256), 0, stream,
                     fh, fl, Bth, Btl, aw, g, sl, sr);
  hipLaunchKernelGGL(k_sort, dim3(B_ * H_), dim3(1024), 0, stream, sr, sv, si);
  hipLaunchKernelGGL(k_split, dim3(B_ * H_ * N_ / 256), dim3(256), 0, stream, sl, sv, parr);
  hipLaunchKernelGGL(k_chunks, dim3(B_ * H_ * NCHUNK), dim3(64), 0, stream, g, sv, si,
                     P1, P2, Zpe1, Zpe2, C1, C2, Zc1, Zc2);
  hipLaunchKernelGGL(k_scan, dim3(B_ * H_), dim3(64), 0, stream, C1, C2, Zc1, Zc2, U1, U2, Zb1, Zb2);
  hipLaunchKernelGGL(k_out, dim3(B_ * N_ * H_ / 4), dim3(256), 0, stream,
                     sl, sv, parr, P1, P2, Zpe1, Zpe2, U1, U2, Zb1, Zb2, out);
}